// Round 1
// baseline (952.608 us; speedup 1.0000x reference)
//
#include <hip/hip_runtime.h>
#include <hip/hip_bf16.h>

#define N_IN 512
#define HID 32
#define OUTD 40

__global__ void k_init_cnt(float* cnt, int n) {
    int i = blockIdx.x * blockDim.x + threadIdx.x;
    if (i < n) cnt[i] = 1.0f;  // self-loop contributes 1 to degree
}

__global__ void k_count(const int* __restrict__ dst, float* cnt, int e) {
    int i = blockIdx.x * blockDim.x + threadIdx.x;
    if (i < e) atomicAdd(&cnt[dst[i]], 1.0f);
}

__global__ void k_rsqrt(float* d, int n) {
    int i = blockIdx.x * blockDim.x + threadIdx.x;
    if (i < n) d[i] = rsqrtf(d[i]);
}

// gemm1: h = x@W1 ; g1 = dinv*h ; acc1 = g1 (self-loop pre-seeded)
#define G1_T 128
#define G1_KC 64
#define G1_STR 68  // 64 + 4 pad: breaks LDS bank aliasing for float4 reads
__global__ __launch_bounds__(G1_T) void k_gemm1(
    const float* __restrict__ x, const float* __restrict__ W1,
    const float* __restrict__ dinv, float* __restrict__ g1,
    float* __restrict__ acc1, int n)
{
    __shared__ float xs[G1_T * G1_STR];
    const int t = threadIdx.x;
    const int row0 = blockIdx.x * G1_T;

    float acc[HID];
#pragma unroll
    for (int c = 0; c < HID; c++) acc[c] = 0.f;

    for (int kc = 0; kc < N_IN; kc += G1_KC) {
        __syncthreads();
        // stage 128 rows x 64 floats, coalesced (16 consecutive float4 per row-segment)
#pragma unroll
        for (int i = 0; i < 16; i++) {
            int r  = i * 8 + (t >> 4);
            int k4 = (t & 15) * 4;
            float4 v = make_float4(0.f, 0.f, 0.f, 0.f);
            int row = row0 + r;
            if (row < n) v = *(const float4*)&x[(size_t)row * N_IN + kc + k4];
            *(float4*)&xs[r * G1_STR + k4] = v;
        }
        __syncthreads();
#pragma unroll
        for (int kk = 0; kk < G1_KC; kk += 4) {
            float4 xv = *(const float4*)&xs[t * G1_STR + kk];
            const float* wr = &W1[(kc + kk) * HID];  // uniform index -> s_load
#pragma unroll
            for (int c = 0; c < HID; c++) acc[c] += xv.x * wr[c];
#pragma unroll
            for (int c = 0; c < HID; c++) acc[c] += xv.y * wr[HID + c];
#pragma unroll
            for (int c = 0; c < HID; c++) acc[c] += xv.z * wr[2 * HID + c];
#pragma unroll
            for (int c = 0; c < HID; c++) acc[c] += xv.w * wr[3 * HID + c];
        }
    }

    int row = row0 + t;
    if (row < n) {
        float dv = dinv[row];
        float4* gp = (float4*)&g1[(size_t)row * HID];
        float4* ap = (float4*)&acc1[(size_t)row * HID];
#pragma unroll
        for (int c4 = 0; c4 < HID / 4; c4++) {
            float4 v;
            v.x = acc[c4 * 4 + 0] * dv;
            v.y = acc[c4 * 4 + 1] * dv;
            v.z = acc[c4 * 4 + 2] * dv;
            v.w = acc[c4 * 4 + 3] * dv;
            gp[c4] = v;
            ap[c4] = v;
        }
    }
}

__global__ void k_scatter32(const int* __restrict__ src, const int* __restrict__ dst,
                            const float* __restrict__ g, float* acc, long total)
{
    long i = (long)blockIdx.x * blockDim.x + threadIdx.x;
    if (i >= total) return;
    int e = (int)(i >> 5);
    int c = (int)(i & 31);
    int s = src[e], d = dst[e];
    atomicAdd(&acc[(size_t)d * HID + c], g[(size_t)s * HID + c]);
}

__global__ void k_scatter40(const int* __restrict__ src, const int* __restrict__ dst,
                            const float* __restrict__ g, float* acc, long total)
{
    long i = (long)blockIdx.x * blockDim.x + threadIdx.x;
    if (i >= total) return;
    int e = (int)(i / OUTD);
    int c = (int)(i - (long)e * OUTD);
    int s = src[e], d = dst[e];
    atomicAdd(&acc[(size_t)d * OUTD + c], g[(size_t)s * OUTD + c]);
}

// gemm2 fused: t = relu(dinv*acc1 + b1); h2 = t@W2; g2 = dinv*h2; dout init = g2 (self-loop)
__global__ void k_gemm2(const float* __restrict__ acc1, const float* __restrict__ b1,
                        const float* __restrict__ W2, const float* __restrict__ dinv,
                        float* __restrict__ g2, float* __restrict__ dout, int n)
{
    int r = blockIdx.x * blockDim.x + threadIdx.x;
    if (r >= n) return;
    float dv = dinv[r];
    float h[HID];
#pragma unroll
    for (int k4 = 0; k4 < HID / 4; k4++) {
        float4 v  = *(const float4*)&acc1[(size_t)r * HID + k4 * 4];
        float4 bv = *(const float4*)&b1[k4 * 4];
        h[k4 * 4 + 0] = fmaxf(v.x * dv + bv.x, 0.f);
        h[k4 * 4 + 1] = fmaxf(v.y * dv + bv.y, 0.f);
        h[k4 * 4 + 2] = fmaxf(v.z * dv + bv.z, 0.f);
        h[k4 * 4 + 3] = fmaxf(v.w * dv + bv.w, 0.f);
    }
    float o[OUTD];
#pragma unroll
    for (int c = 0; c < OUTD; c++) o[c] = 0.f;
#pragma unroll
    for (int k = 0; k < HID; k++) {
        float hv = h[k];
        const float* wr = &W2[k * OUTD];  // uniform -> s_load
#pragma unroll
        for (int c = 0; c < OUTD; c++) o[c] += hv * wr[c];
    }
    float* gp = &g2[(size_t)r * OUTD];
    float* op = &dout[(size_t)r * OUTD];
#pragma unroll
    for (int c4 = 0; c4 < OUTD / 4; c4++) {
        float4 v;
        v.x = o[c4 * 4 + 0] * dv;
        v.y = o[c4 * 4 + 1] * dv;
        v.z = o[c4 * 4 + 2] * dv;
        v.w = o[c4 * 4 + 3] * dv;
        *(float4*)&gp[c4 * 4] = v;
        *(float4*)&op[c4 * 4] = v;
    }
}

__global__ void k_final(float* out, const float* __restrict__ dinv,
                        const float* __restrict__ b2, long total)
{
    long i = (long)blockIdx.x * blockDim.x + threadIdx.x;
    if (i >= total) return;
    int r = (int)(i / OUTD);
    int c = (int)(i - (long)r * OUTD);
    out[i] = out[i] * dinv[r] + b2[c];
}

extern "C" void kernel_launch(void* const* d_in, const int* in_sizes, int n_in,
                              void* d_out, int out_size, void* d_ws, size_t ws_size,
                              hipStream_t stream)
{
    const float* x  = (const float*)d_in[0];
    const int*   ei = (const int*)d_in[1];
    const float* W1 = (const float*)d_in[2];
    const float* b1 = (const float*)d_in[3];
    const float* W2 = (const float*)d_in[4];
    const float* b2 = (const float*)d_in[5];
    float* out = (float*)d_out;

    const int n = in_sizes[0] / N_IN;  // 100000
    const int e = in_sizes[1] / 2;     // 1600000
    const int* src = ei;
    const int* dst = ei + e;

    float* ws   = (float*)d_ws;
    float* dinv = ws;                          // n floats (n mult of 4 -> aligned)
    float* g1   = ws + (size_t)((n + 3) & ~3); // n*32
    float* acc1 = g1 + (size_t)n * HID;        // n*32
    float* g2   = acc1 + (size_t)n * HID;      // n*40

    k_init_cnt<<<(n + 255) / 256, 256, 0, stream>>>(dinv, n);
    k_count<<<(e + 255) / 256, 256, 0, stream>>>(dst, dinv, e);
    k_rsqrt<<<(n + 255) / 256, 256, 0, stream>>>(dinv, n);

    k_gemm1<<<(n + G1_T - 1) / G1_T, G1_T, 0, stream>>>(x, W1, dinv, g1, acc1, n);

    long t1 = (long)e * HID;
    k_scatter32<<<(int)((t1 + 255) / 256), 256, 0, stream>>>(src, dst, g1, acc1, t1);

    k_gemm2<<<(n + 255) / 256, 256, 0, stream>>>(acc1, b1, W2, dinv, g2, out, n);

    long t2 = (long)e * OUTD;
    k_scatter40<<<(int)((t2 + 255) / 256), 256, 0, stream>>>(src, dst, g2, out, t2);

    long t3 = (long)n * OUTD;
    k_final<<<(int)((t3 + 255) / 256), 256, 0, stream>>>(out, dinv, b2, t3);
}

// Round 2
// 702.567 us; speedup vs baseline: 1.3559x; 1.3559x over previous
//
#include <hip/hip_runtime.h>
#include <hip/hip_bf16.h>

#define N_IN 512
#define HID 32
#define OUTD 40

// ---------------- degree / CSR build ----------------

__global__ void k_zero_i(int* p, int n) {
    int i = blockIdx.x * blockDim.x + threadIdx.x;
    if (i < n) p[i] = 0;
}

__global__ void k_count(const int* __restrict__ dst, int* cnt, int e) {
    int i = blockIdx.x * blockDim.x + threadIdx.x;
    if (i < e) atomicAdd(&cnt[dst[i]], 1);
}

// block-local exclusive scan: 256 threads x 4 elems = 1024/block
__global__ __launch_bounds__(256) void k_scan1(const int* __restrict__ cnt,
                                               int* __restrict__ offs,
                                               int* __restrict__ bsums, int n)
{
    __shared__ int sm[256];
    int t = threadIdx.x;
    int base = blockIdx.x * 1024 + t * 4;
    int a0 = (base + 0 < n) ? cnt[base + 0] : 0;
    int a1 = (base + 1 < n) ? cnt[base + 1] : 0;
    int a2 = (base + 2 < n) ? cnt[base + 2] : 0;
    int a3 = (base + 3 < n) ? cnt[base + 3] : 0;
    int s = a0 + a1 + a2 + a3;
    sm[t] = s;
    __syncthreads();
#pragma unroll
    for (int off = 1; off < 256; off <<= 1) {
        int v = (t >= off) ? sm[t - off] : 0;
        __syncthreads();
        sm[t] += v;
        __syncthreads();
    }
    int excl = sm[t] - s;  // exclusive within block
    if (base + 0 < n) offs[base + 0] = excl;
    if (base + 1 < n) offs[base + 1] = excl + a0;
    if (base + 2 < n) offs[base + 2] = excl + a0 + a1;
    if (base + 3 < n) offs[base + 3] = excl + a0 + a1 + a2;
    if (t == 255) bsums[blockIdx.x] = sm[255];
}

// single-block exclusive scan of block sums (nb <= 256)
__global__ __launch_bounds__(256) void k_scan2(int* bsums, int nb)
{
    __shared__ int sm[256];
    int t = threadIdx.x;
    int s = (t < nb) ? bsums[t] : 0;
    sm[t] = s;
    __syncthreads();
#pragma unroll
    for (int off = 1; off < 256; off <<= 1) {
        int v = (t >= off) ? sm[t - off] : 0;
        __syncthreads();
        sm[t] += v;
        __syncthreads();
    }
    if (t < nb) bsums[t] = sm[t] - s;  // exclusive
}

// finalize offsets, init cursor, compute dinv = rsqrt(1 + indeg)
__global__ void k_scan3(int* __restrict__ offs, int* __restrict__ cursor,
                        const int* __restrict__ bsums, const int* __restrict__ cnt,
                        float* __restrict__ dinv, int n)
{
    int i = blockIdx.x * blockDim.x + threadIdx.x;
    if (i >= n) return;
    int o = offs[i] + bsums[i >> 10];
    offs[i] = o;
    cursor[i] = o;
    dinv[i] = rsqrtf((float)(cnt[i] + 1));
}

__global__ void k_fill(const int* __restrict__ src, const int* __restrict__ dst,
                       int* cursor, int* __restrict__ csr, int e)
{
    int i = blockIdx.x * blockDim.x + threadIdx.x;
    if (i >= e) return;
    int p = atomicAdd(&cursor[dst[i]], 1);
    csr[p] = src[i];
}

// ---------------- gemm1: g1 = dinv * (x @ W1) ----------------
#define G1_T 128
#define G1_KC 64
#define G1_STR 68
__global__ __launch_bounds__(G1_T) void k_gemm1(
    const float* __restrict__ x, const float* __restrict__ W1,
    const float* __restrict__ dinv, float* __restrict__ g1, int n)
{
    __shared__ float xs[G1_T * G1_STR];
    const int t = threadIdx.x;
    const int row0 = blockIdx.x * G1_T;

    float acc[HID];
#pragma unroll
    for (int c = 0; c < HID; c++) acc[c] = 0.f;

    for (int kc = 0; kc < N_IN; kc += G1_KC) {
        __syncthreads();
#pragma unroll
        for (int i = 0; i < 16; i++) {
            int r  = i * 8 + (t >> 4);
            int k4 = (t & 15) * 4;
            float4 v = make_float4(0.f, 0.f, 0.f, 0.f);
            int row = row0 + r;
            if (row < n) v = *(const float4*)&x[(size_t)row * N_IN + kc + k4];
            *(float4*)&xs[r * G1_STR + k4] = v;
        }
        __syncthreads();
#pragma unroll
        for (int kk = 0; kk < G1_KC; kk += 4) {
            float4 xv = *(const float4*)&xs[t * G1_STR + kk];
            const float* wr = &W1[(kc + kk) * HID];  // uniform -> s_load
#pragma unroll
            for (int c = 0; c < HID; c++) acc[c] += xv.x * wr[c];
#pragma unroll
            for (int c = 0; c < HID; c++) acc[c] += xv.y * wr[HID + c];
#pragma unroll
            for (int c = 0; c < HID; c++) acc[c] += xv.z * wr[2 * HID + c];
#pragma unroll
            for (int c = 0; c < HID; c++) acc[c] += xv.w * wr[3 * HID + c];
        }
    }

    int row = row0 + t;
    if (row < n) {
        float dv = dinv[row];
        float4* gp = (float4*)&g1[(size_t)row * HID];
#pragma unroll
        for (int c4 = 0; c4 < HID / 4; c4++) {
            float4 v;
            v.x = acc[c4 * 4 + 0] * dv;
            v.y = acc[c4 * 4 + 1] * dv;
            v.z = acc[c4 * 4 + 2] * dv;
            v.w = acc[c4 * 4 + 3] * dv;
            gp[c4] = v;
        }
    }
}

// ---------------- gather-aggregate (CSR), thread = (node, float4 chunk) ----------------

// acc1[r] = g1[r] + sum_{s in in(r)} g1[s]   (32 cols -> 8 chunks/node)
__global__ void k_agg32(const int* __restrict__ csr, const int* __restrict__ offs,
                        const int* __restrict__ cnt, const float* __restrict__ g,
                        float* __restrict__ acc1, int n)
{
    int i = blockIdx.x * blockDim.x + threadIdx.x;
    if (i >= n * (HID / 4)) return;
    int r  = i >> 3;
    int c4 = i & 7;
    const float* gc = g + c4 * 4;
    float4 acc = *(const float4*)&gc[(size_t)r * HID];  // self loop
    int s0 = offs[r], d = cnt[r];
    for (int j = 0; j < d; j++) {
        int s = csr[s0 + j];
        float4 v = *(const float4*)&gc[(size_t)s * HID];
        acc.x += v.x; acc.y += v.y; acc.z += v.z; acc.w += v.w;
    }
    *(float4*)&acc1[(size_t)r * HID + c4 * 4] = acc;
}

// out[r] = dinv[r] * (g2[r] + sum_{s in in(r)} g2[s]) + b2   (40 cols -> 10 chunks/node)
__global__ void k_agg40(const int* __restrict__ csr, const int* __restrict__ offs,
                        const int* __restrict__ cnt, const float* __restrict__ g,
                        const float* __restrict__ dinv, const float* __restrict__ b2,
                        float* __restrict__ out, int n)
{
    int i = blockIdx.x * blockDim.x + threadIdx.x;
    if (i >= n * (OUTD / 4)) return;
    int r  = i / (OUTD / 4);
    int c4 = i - r * (OUTD / 4);
    const float* gc = g + c4 * 4;
    float4 acc = *(const float4*)&gc[(size_t)r * OUTD];  // self loop
    int s0 = offs[r], d = cnt[r];
    for (int j = 0; j < d; j++) {
        int s = csr[s0 + j];
        float4 v = *(const float4*)&gc[(size_t)s * OUTD];
        acc.x += v.x; acc.y += v.y; acc.z += v.z; acc.w += v.w;
    }
    float dv = dinv[r];
    float4 bv = *(const float4*)&b2[c4 * 4];
    float4 o;
    o.x = acc.x * dv + bv.x;
    o.y = acc.y * dv + bv.y;
    o.z = acc.z * dv + bv.z;
    o.w = acc.w * dv + bv.w;
    *(float4*)&out[(size_t)r * OUTD + c4 * 4] = o;
}

// ---------------- gemm2: g2 = dinv * (relu(dinv*acc1 + b1) @ W2) ----------------
__global__ void k_gemm2(const float* __restrict__ acc1, const float* __restrict__ b1,
                        const float* __restrict__ W2, const float* __restrict__ dinv,
                        float* __restrict__ g2, int n)
{
    int r = blockIdx.x * blockDim.x + threadIdx.x;
    if (r >= n) return;
    float dv = dinv[r];
    float h[HID];
#pragma unroll
    for (int k4 = 0; k4 < HID / 4; k4++) {
        float4 v  = *(const float4*)&acc1[(size_t)r * HID + k4 * 4];
        float4 bv = *(const float4*)&b1[k4 * 4];
        h[k4 * 4 + 0] = fmaxf(v.x * dv + bv.x, 0.f);
        h[k4 * 4 + 1] = fmaxf(v.y * dv + bv.y, 0.f);
        h[k4 * 4 + 2] = fmaxf(v.z * dv + bv.z, 0.f);
        h[k4 * 4 + 3] = fmaxf(v.w * dv + bv.w, 0.f);
    }
    float o[OUTD];
#pragma unroll
    for (int c = 0; c < OUTD; c++) o[c] = 0.f;
#pragma unroll
    for (int k = 0; k < HID; k++) {
        float hv = h[k];
        const float* wr = &W2[k * OUTD];  // uniform -> s_load
#pragma unroll
        for (int c = 0; c < OUTD; c++) o[c] += hv * wr[c];
    }
    float* gp = &g2[(size_t)r * OUTD];
#pragma unroll
    for (int c4 = 0; c4 < OUTD / 4; c4++) {
        float4 v;
        v.x = o[c4 * 4 + 0] * dv;
        v.y = o[c4 * 4 + 1] * dv;
        v.z = o[c4 * 4 + 2] * dv;
        v.w = o[c4 * 4 + 3] * dv;
        *(float4*)&gp[c4 * 4] = v;
    }
}

extern "C" void kernel_launch(void* const* d_in, const int* in_sizes, int n_in,
                              void* d_out, int out_size, void* d_ws, size_t ws_size,
                              hipStream_t stream)
{
    const float* x  = (const float*)d_in[0];
    const int*   ei = (const int*)d_in[1];
    const float* W1 = (const float*)d_in[2];
    const float* b1 = (const float*)d_in[3];
    const float* W2 = (const float*)d_in[4];
    const float* b2 = (const float*)d_in[5];
    float* out = (float*)d_out;

    const int n = in_sizes[0] / N_IN;  // 100000
    const int e = in_sizes[1] / 2;     // 1600000
    const int* src = ei;
    const int* dst = ei + e;

    // workspace layout (all 4-byte elems)
    char* w = (char*)d_ws;
    float* dinv   = (float*)w;            w += sizeof(float) * (size_t)((n + 3) & ~3);
    float* g1     = (float*)w;            w += sizeof(float) * (size_t)n * HID;
    float* acc1   = (float*)w;            w += sizeof(float) * (size_t)n * HID;
    float* g2     = (float*)w;            w += sizeof(float) * (size_t)n * OUTD;
    int*   cnt    = (int*)w;              w += sizeof(int) * (size_t)((n + 3) & ~3);
    int*   offs   = (int*)w;              w += sizeof(int) * (size_t)((n + 3) & ~3);
    int*   cursor = (int*)w;              w += sizeof(int) * (size_t)((n + 3) & ~3);
    int*   bsums  = (int*)w;              w += sizeof(int) * 1024;
    int*   csr    = (int*)w;              w += sizeof(int) * (size_t)e;

    const int nb = (n + 1023) / 1024;  // scan blocks (<=256)

    k_zero_i<<<(n + 255) / 256, 256, 0, stream>>>(cnt, n);
    k_count<<<(e + 255) / 256, 256, 0, stream>>>(dst, cnt, e);
    k_scan1<<<nb, 256, 0, stream>>>(cnt, offs, bsums, n);
    k_scan2<<<1, 256, 0, stream>>>(bsums, nb);
    k_scan3<<<(n + 255) / 256, 256, 0, stream>>>(offs, cursor, bsums, cnt, dinv, n);
    k_fill<<<(e + 255) / 256, 256, 0, stream>>>(src, dst, cursor, csr, e);

    k_gemm1<<<(n + G1_T - 1) / G1_T, G1_T, 0, stream>>>(x, W1, dinv, g1, n);

    int t32 = n * (HID / 4);
    k_agg32<<<(t32 + 255) / 256, 256, 0, stream>>>(csr, offs, cnt, g1, acc1, n);

    k_gemm2<<<(n + 255) / 256, 256, 0, stream>>>(acc1, b1, W2, dinv, g2, n);

    int t40 = n * (OUTD / 4);
    k_agg40<<<(t40 + 255) / 256, 256, 0, stream>>>(csr, offs, cnt, g2, dinv, b2, out, n);
}

// Round 3
// 638.530 us; speedup vs baseline: 1.4919x; 1.1003x over previous
//
#include <hip/hip_runtime.h>
#include <hip/hip_bf16.h>

#define N_IN 512
#define HID 32
#define OUTD 40

// ---------------- degree / CSR build ----------------

__global__ void k_zero_i(int* p, int n) {
    int i = blockIdx.x * blockDim.x + threadIdx.x;
    if (i < n) p[i] = 0;
}

__global__ void k_count(const int* __restrict__ dst, int* cnt, int e) {
    int i = blockIdx.x * blockDim.x + threadIdx.x;
    if (i < e) atomicAdd(&cnt[dst[i]], 1);
}

// block-local exclusive scan: 256 threads x 4 elems = 1024/block
__global__ __launch_bounds__(256) void k_scan1(const int* __restrict__ cnt,
                                               int* __restrict__ offs,
                                               int* __restrict__ bsums, int n)
{
    __shared__ int sm[256];
    int t = threadIdx.x;
    int base = blockIdx.x * 1024 + t * 4;
    int a0 = (base + 0 < n) ? cnt[base + 0] : 0;
    int a1 = (base + 1 < n) ? cnt[base + 1] : 0;
    int a2 = (base + 2 < n) ? cnt[base + 2] : 0;
    int a3 = (base + 3 < n) ? cnt[base + 3] : 0;
    int s = a0 + a1 + a2 + a3;
    sm[t] = s;
    __syncthreads();
#pragma unroll
    for (int off = 1; off < 256; off <<= 1) {
        int v = (t >= off) ? sm[t - off] : 0;
        __syncthreads();
        sm[t] += v;
        __syncthreads();
    }
    int excl = sm[t] - s;  // exclusive within block
    if (base + 0 < n) offs[base + 0] = excl;
    if (base + 1 < n) offs[base + 1] = excl + a0;
    if (base + 2 < n) offs[base + 2] = excl + a0 + a1;
    if (base + 3 < n) offs[base + 3] = excl + a0 + a1 + a2;
    if (t == 255) bsums[blockIdx.x] = sm[255];
}

// single-block exclusive scan of block sums (nb <= 256)
__global__ __launch_bounds__(256) void k_scan2(int* bsums, int nb)
{
    __shared__ int sm[256];
    int t = threadIdx.x;
    int s = (t < nb) ? bsums[t] : 0;
    sm[t] = s;
    __syncthreads();
#pragma unroll
    for (int off = 1; off < 256; off <<= 1) {
        int v = (t >= off) ? sm[t - off] : 0;
        __syncthreads();
        sm[t] += v;
        __syncthreads();
    }
    if (t < nb) bsums[t] = sm[t] - s;  // exclusive
}

// finalize offsets, init cursor, compute dinv = rsqrt(1 + indeg)
__global__ void k_scan3(int* __restrict__ offs, int* __restrict__ cursor,
                        const int* __restrict__ bsums, const int* __restrict__ cnt,
                        float* __restrict__ dinv, int n)
{
    int i = blockIdx.x * blockDim.x + threadIdx.x;
    if (i >= n) return;
    int o = offs[i] + bsums[i >> 10];
    offs[i] = o;
    cursor[i] = o;
    dinv[i] = rsqrtf((float)(cnt[i] + 1));
}

__global__ void k_fill(const int* __restrict__ src, const int* __restrict__ dst,
                       int* cursor, int* __restrict__ csr, int e)
{
    int i = blockIdx.x * blockDim.x + threadIdx.x;
    if (i >= e) return;
    int p = atomicAdd(&cursor[dst[i]], 1);
    csr[p] = src[i];
}

// ---------------- gemm1: g1 = dinv * (x @ W1) ----------------
// 256 threads = 4 waves; block covers 64 rows; wave w owns cols [w*8, w*8+8);
// lane = row. W1 index wave-uniform (readfirstlane) -> scalar loads.
#define G1_ROWS 64
#define G1_T 256
#define G1_KC 64
#define G1_STR 68  // 64 + 4 pad: measured conflict-free with b128 reads
__global__ __launch_bounds__(G1_T) void k_gemm1(
    const float* __restrict__ x, const float* __restrict__ W1,
    const float* __restrict__ dinv, float* __restrict__ g1, int n)
{
    __shared__ float xs[G1_ROWS * G1_STR];  // 17.4 KB
    const int t = threadIdx.x;
    const int lane = t & 63;
    const int cg = __builtin_amdgcn_readfirstlane((t >> 6) * 8);  // wave-uniform col base
    const int row0 = blockIdx.x * G1_ROWS;

    float acc[8];
#pragma unroll
    for (int c = 0; c < 8; c++) acc[c] = 0.f;

    for (int kc = 0; kc < N_IN; kc += G1_KC) {
        __syncthreads();
        // stage 64 rows x 64 floats = 1024 float4, 256 threads -> 4 each, coalesced
#pragma unroll
        for (int i = 0; i < 4; i++) {
            int r  = i * 16 + (t >> 4);
            int k4 = (t & 15) * 4;
            float4 v = make_float4(0.f, 0.f, 0.f, 0.f);
            int row = row0 + r;
            if (row < n) v = *(const float4*)&x[(size_t)row * N_IN + kc + k4];
            *(float4*)&xs[r * G1_STR + k4] = v;
        }
        __syncthreads();
#pragma unroll
        for (int kk = 0; kk < G1_KC; kk += 4) {
            float4 xv = *(const float4*)&xs[lane * G1_STR + kk];
            const float* wr = &W1[(kc + kk) * HID + cg];  // wave-uniform -> s_load
#pragma unroll
            for (int c = 0; c < 8; c++) acc[c] += xv.x * wr[c];
#pragma unroll
            for (int c = 0; c < 8; c++) acc[c] += xv.y * wr[HID + c];
#pragma unroll
            for (int c = 0; c < 8; c++) acc[c] += xv.z * wr[2 * HID + c];
#pragma unroll
            for (int c = 0; c < 8; c++) acc[c] += xv.w * wr[3 * HID + c];
        }
    }

    int row = row0 + lane;
    if (row < n) {
        float dv = dinv[row];
        float4 v0, v1;
        v0.x = acc[0] * dv; v0.y = acc[1] * dv; v0.z = acc[2] * dv; v0.w = acc[3] * dv;
        v1.x = acc[4] * dv; v1.y = acc[5] * dv; v1.z = acc[6] * dv; v1.w = acc[7] * dv;
        *(float4*)&g1[(size_t)row * HID + cg]     = v0;
        *(float4*)&g1[(size_t)row * HID + cg + 4] = v1;
    }
}

// ---------------- gather-aggregate (CSR), thread = (node, float4 chunk) ----------------

// acc1[r] = g1[r] + sum_{s in in(r)} g1[s]   (32 cols -> 8 chunks/node)
__global__ void k_agg32(const int* __restrict__ csr, const int* __restrict__ offs,
                        const int* __restrict__ cnt, const float* __restrict__ g,
                        float* __restrict__ acc1, int n)
{
    int i = blockIdx.x * blockDim.x + threadIdx.x;
    if (i >= n * (HID / 4)) return;
    int r  = i >> 3;
    int c4 = i & 7;
    const float* gc = g + c4 * 4;
    float4 acc = *(const float4*)&gc[(size_t)r * HID];  // self loop
    int s0 = offs[r], d = cnt[r];
    for (int j = 0; j < d; j++) {
        int s = csr[s0 + j];
        float4 v = *(const float4*)&gc[(size_t)s * HID];
        acc.x += v.x; acc.y += v.y; acc.z += v.z; acc.w += v.w;
    }
    *(float4*)&acc1[(size_t)r * HID + c4 * 4] = acc;
}

// out[r] = dinv[r] * (g2[r] + sum_{s in in(r)} g2[s]) + b2   (40 cols -> 10 chunks/node)
__global__ void k_agg40(const int* __restrict__ csr, const int* __restrict__ offs,
                        const int* __restrict__ cnt, const float* __restrict__ g,
                        const float* __restrict__ dinv, const float* __restrict__ b2,
                        float* __restrict__ out, int n)
{
    int i = blockIdx.x * blockDim.x + threadIdx.x;
    if (i >= n * (OUTD / 4)) return;
    int r  = i / (OUTD / 4);
    int c4 = i - r * (OUTD / 4);
    const float* gc = g + c4 * 4;
    float4 acc = *(const float4*)&gc[(size_t)r * OUTD];  // self loop
    int s0 = offs[r], d = cnt[r];
    for (int j = 0; j < d; j++) {
        int s = csr[s0 + j];
        float4 v = *(const float4*)&gc[(size_t)s * OUTD];
        acc.x += v.x; acc.y += v.y; acc.z += v.z; acc.w += v.w;
    }
    float dv = dinv[r];
    float4 bv = *(const float4*)&b2[c4 * 4];
    float4 o;
    o.x = acc.x * dv + bv.x;
    o.y = acc.y * dv + bv.y;
    o.z = acc.z * dv + bv.z;
    o.w = acc.w * dv + bv.w;
    *(float4*)&out[(size_t)r * OUTD + c4 * 4] = o;
}

// ---------------- gemm2: g2 = dinv * (relu(dinv*acc1 + b1) @ W2) ----------------
__global__ void k_gemm2(const float* __restrict__ acc1, const float* __restrict__ b1,
                        const float* __restrict__ W2, const float* __restrict__ dinv,
                        float* __restrict__ g2, int n)
{
    int r = blockIdx.x * blockDim.x + threadIdx.x;
    if (r >= n) return;
    float dv = dinv[r];
    float h[HID];
#pragma unroll
    for (int k4 = 0; k4 < HID / 4; k4++) {
        float4 v  = *(const float4*)&acc1[(size_t)r * HID + k4 * 4];
        float4 bv = *(const float4*)&b1[k4 * 4];
        h[k4 * 4 + 0] = fmaxf(v.x * dv + bv.x, 0.f);
        h[k4 * 4 + 1] = fmaxf(v.y * dv + bv.y, 0.f);
        h[k4 * 4 + 2] = fmaxf(v.z * dv + bv.z, 0.f);
        h[k4 * 4 + 3] = fmaxf(v.w * dv + bv.w, 0.f);
    }
    float o[OUTD];
#pragma unroll
    for (int c = 0; c < OUTD; c++) o[c] = 0.f;
#pragma unroll
    for (int k = 0; k < HID; k++) {
        float hv = h[k];
        const float* wr = &W2[k * OUTD];  // uniform -> s_load
#pragma unroll
        for (int c = 0; c < OUTD; c++) o[c] += hv * wr[c];
    }
    float* gp = &g2[(size_t)r * OUTD];
#pragma unroll
    for (int c4 = 0; c4 < OUTD / 4; c4++) {
        float4 v;
        v.x = o[c4 * 4 + 0] * dv;
        v.y = o[c4 * 4 + 1] * dv;
        v.z = o[c4 * 4 + 2] * dv;
        v.w = o[c4 * 4 + 3] * dv;
        *(float4*)&gp[c4 * 4] = v;
    }
}

extern "C" void kernel_launch(void* const* d_in, const int* in_sizes, int n_in,
                              void* d_out, int out_size, void* d_ws, size_t ws_size,
                              hipStream_t stream)
{
    const float* x  = (const float*)d_in[0];
    const int*   ei = (const int*)d_in[1];
    const float* W1 = (const float*)d_in[2];
    const float* b1 = (const float*)d_in[3];
    const float* W2 = (const float*)d_in[4];
    const float* b2 = (const float*)d_in[5];
    float* out = (float*)d_out;

    const int n = in_sizes[0] / N_IN;  // 100000
    const int e = in_sizes[1] / 2;     // 1600000
    const int* src = ei;
    const int* dst = ei + e;

    // workspace layout (all 4-byte elems)
    char* w = (char*)d_ws;
    float* dinv   = (float*)w;            w += sizeof(float) * (size_t)((n + 3) & ~3);
    float* g1     = (float*)w;            w += sizeof(float) * (size_t)n * HID;
    float* acc1   = (float*)w;            w += sizeof(float) * (size_t)n * HID;
    float* g2     = (float*)w;            w += sizeof(float) * (size_t)n * OUTD;
    int*   cnt    = (int*)w;              w += sizeof(int) * (size_t)((n + 3) & ~3);
    int*   offs   = (int*)w;              w += sizeof(int) * (size_t)((n + 3) & ~3);
    int*   cursor = (int*)w;              w += sizeof(int) * (size_t)((n + 3) & ~3);
    int*   bsums  = (int*)w;              w += sizeof(int) * 1024;
    int*   csr    = (int*)w;              w += sizeof(int) * (size_t)e;

    const int nb = (n + 1023) / 1024;  // scan blocks (<=256)

    k_zero_i<<<(n + 255) / 256, 256, 0, stream>>>(cnt, n);
    k_count<<<(e + 255) / 256, 256, 0, stream>>>(dst, cnt, e);
    k_scan1<<<nb, 256, 0, stream>>>(cnt, offs, bsums, n);
    k_scan2<<<1, 256, 0, stream>>>(bsums, nb);
    k_scan3<<<(n + 255) / 256, 256, 0, stream>>>(offs, cursor, bsums, cnt, dinv, n);
    k_fill<<<(e + 255) / 256, 256, 0, stream>>>(src, dst, cursor, csr, e);

    k_gemm1<<<(n + G1_ROWS - 1) / G1_ROWS, G1_T, 0, stream>>>(x, W1, dinv, g1, n);

    int t32 = n * (HID / 4);
    k_agg32<<<(t32 + 255) / 256, 256, 0, stream>>>(csr, offs, cnt, g1, acc1, n);

    k_gemm2<<<(n + 255) / 256, 256, 0, stream>>>(acc1, b1, W2, dinv, g2, n);

    int t40 = n * (OUTD / 4);
    k_agg40<<<(t40 + 255) / 256, 256, 0, stream>>>(csr, offs, cnt, g2, dinv, b2, out, n);
}

// Round 4
// 631.444 us; speedup vs baseline: 1.5086x; 1.0112x over previous
//
#include <hip/hip_runtime.h>
#include <hip/hip_bf16.h>

#define N_IN 512
#define HID 32
#define OUTD 40
#define NWIN 8  // fill windows: csr region per window ~800 KB -> L2-resident writes

// ---------------- degree / CSR build ----------------

__global__ void k_zero_i(int* p, int n) {
    int i = blockIdx.x * blockDim.x + threadIdx.x;
    if (i < n) p[i] = 0;
}

__global__ void k_count(const int* __restrict__ dst, int* cnt, int e) {
    int i = blockIdx.x * blockDim.x + threadIdx.x;
    if (i < e) atomicAdd(&cnt[dst[i]], 1);
}

// block-local exclusive scan: 256 threads x 4 elems = 1024/block
__global__ __launch_bounds__(256) void k_scan1(const int* __restrict__ cnt,
                                               int* __restrict__ offs,
                                               int* __restrict__ bsums, int n)
{
    __shared__ int sm[256];
    int t = threadIdx.x;
    int base = blockIdx.x * 1024 + t * 4;
    int a0 = (base + 0 < n) ? cnt[base + 0] : 0;
    int a1 = (base + 1 < n) ? cnt[base + 1] : 0;
    int a2 = (base + 2 < n) ? cnt[base + 2] : 0;
    int a3 = (base + 3 < n) ? cnt[base + 3] : 0;
    int s = a0 + a1 + a2 + a3;
    sm[t] = s;
    __syncthreads();
#pragma unroll
    for (int off = 1; off < 256; off <<= 1) {
        int v = (t >= off) ? sm[t - off] : 0;
        __syncthreads();
        sm[t] += v;
        __syncthreads();
    }
    int excl = sm[t] - s;
    if (base + 0 < n) offs[base + 0] = excl;
    if (base + 1 < n) offs[base + 1] = excl + a0;
    if (base + 2 < n) offs[base + 2] = excl + a0 + a1;
    if (base + 3 < n) offs[base + 3] = excl + a0 + a1 + a2;
    if (t == 255) bsums[blockIdx.x] = sm[255];
}

// single-block exclusive scan of block sums (nb <= 256)
__global__ __launch_bounds__(256) void k_scan2(int* bsums, int nb)
{
    __shared__ int sm[256];
    int t = threadIdx.x;
    int s = (t < nb) ? bsums[t] : 0;
    sm[t] = s;
    __syncthreads();
#pragma unroll
    for (int off = 1; off < 256; off <<= 1) {
        int v = (t >= off) ? sm[t - off] : 0;
        __syncthreads();
        sm[t] += v;
        __syncthreads();
    }
    if (t < nb) bsums[t] = sm[t] - s;
}

// finalize offsets, init cursor, compute dinv = rsqrt(1 + indeg)
__global__ void k_scan3(int* __restrict__ offs, int* __restrict__ cursor,
                        const int* __restrict__ bsums, const int* __restrict__ cnt,
                        float* __restrict__ dinv, int n)
{
    int i = blockIdx.x * blockDim.x + threadIdx.x;
    if (i >= n) return;
    int o = offs[i] + bsums[i >> 10];
    offs[i] = o;
    cursor[i] = o;
    dinv[i] = rsqrtf((float)(cnt[i] + 1));
}

// windowed fill: only edges with dst in [wlo, whi) -> csr writes land in an
// ~800 KB contiguous region (L2-resident, lines fill before write-back)
__global__ void k_fill_win(const int* __restrict__ src, const int* __restrict__ dst,
                           int* cursor, int* __restrict__ csr, int e, int wlo, int whi)
{
    int i = blockIdx.x * blockDim.x + threadIdx.x;
    if (i >= e) return;
    int d = dst[i];
    if (d < wlo || d >= whi) return;
    int p = atomicAdd(&cursor[d], 1);
    csr[p] = src[i];
}

// ---------------- gemm1: g1 = dinv * (x @ W1) ----------------
#define G1_ROWS 64
#define G1_T 256
#define G1_KC 64
#define G1_STR 68
__global__ __launch_bounds__(G1_T) void k_gemm1(
    const float* __restrict__ x, const float* __restrict__ W1,
    const float* __restrict__ dinv, float* __restrict__ g1, int n)
{
    __shared__ float xs[G1_ROWS * G1_STR];
    const int t = threadIdx.x;
    const int lane = t & 63;
    const int cg = __builtin_amdgcn_readfirstlane((t >> 6) * 8);
    const int row0 = blockIdx.x * G1_ROWS;

    float acc[8];
#pragma unroll
    for (int c = 0; c < 8; c++) acc[c] = 0.f;

    for (int kc = 0; kc < N_IN; kc += G1_KC) {
        __syncthreads();
#pragma unroll
        for (int i = 0; i < 4; i++) {
            int r  = i * 16 + (t >> 4);
            int k4 = (t & 15) * 4;
            float4 v = make_float4(0.f, 0.f, 0.f, 0.f);
            int row = row0 + r;
            if (row < n) v = *(const float4*)&x[(size_t)row * N_IN + kc + k4];
            *(float4*)&xs[r * G1_STR + k4] = v;
        }
        __syncthreads();
#pragma unroll
        for (int kk = 0; kk < G1_KC; kk += 4) {
            float4 xv = *(const float4*)&xs[lane * G1_STR + kk];
            const float* wr = &W1[(kc + kk) * HID + cg];  // wave-uniform -> s_load
#pragma unroll
            for (int c = 0; c < 8; c++) acc[c] += xv.x * wr[c];
#pragma unroll
            for (int c = 0; c < 8; c++) acc[c] += xv.y * wr[HID + c];
#pragma unroll
            for (int c = 0; c < 8; c++) acc[c] += xv.z * wr[2 * HID + c];
#pragma unroll
            for (int c = 0; c < 8; c++) acc[c] += xv.w * wr[3 * HID + c];
        }
    }

    int row = row0 + lane;
    if (row < n) {
        float dv = dinv[row];
        float4 v0, v1;
        v0.x = acc[0] * dv; v0.y = acc[1] * dv; v0.z = acc[2] * dv; v0.w = acc[3] * dv;
        v1.x = acc[4] * dv; v1.y = acc[5] * dv; v1.z = acc[6] * dv; v1.w = acc[7] * dv;
        *(float4*)&g1[(size_t)row * HID + cg]     = v0;
        *(float4*)&g1[(size_t)row * HID + cg + 4] = v1;
    }
}

// ---------------- cooperative gather-aggregate: 16 lanes per node ----------------
// lane sl in [0,16): all 16 lanes load neighbor indices (16/iter), shfl-broadcast;
// lanes sl<CH accumulate float4 chunk sl. Cuts csr re-reads CHx vs chunk-thread version.

// acc1[r] = g1[r] + sum_{s in in(r)} g1[s]
__global__ void k_agg32(const int* __restrict__ csr, const int* __restrict__ offs,
                        const int* __restrict__ cnt, const float* __restrict__ g,
                        float* __restrict__ acc1, int n)
{
    int gid = blockIdx.x * blockDim.x + threadIdx.x;
    int r  = gid >> 4;
    int sl = gid & 15;
    if (r >= n) return;
    int s0 = offs[r], d = cnt[r];
    const bool act = sl < 8;
    const float* gc = g + sl * 4;
    float4 acc = make_float4(0.f, 0.f, 0.f, 0.f);
    if (act) acc = *(const float4*)&gc[(size_t)r * HID];  // self loop
    for (int j0 = 0; j0 < d; j0 += 16) {
        int s = 0;
        if (j0 + sl < d) s = csr[s0 + j0 + sl];
        int m = min(16, d - j0);
        for (int jj = 0; jj < m; jj++) {
            int sj = __shfl(s, jj, 16);
            if (act) {
                float4 v = *(const float4*)&gc[(size_t)sj * HID];
                acc.x += v.x; acc.y += v.y; acc.z += v.z; acc.w += v.w;
            }
        }
    }
    if (act) *(float4*)&acc1[(size_t)r * HID + sl * 4] = acc;
}

// out[r] = dinv[r] * (g2[r] + sum_{s in in(r)} g2[s]) + b2
__global__ void k_agg40(const int* __restrict__ csr, const int* __restrict__ offs,
                        const int* __restrict__ cnt, const float* __restrict__ g,
                        const float* __restrict__ dinv, const float* __restrict__ b2,
                        float* __restrict__ out, int n)
{
    int gid = blockIdx.x * blockDim.x + threadIdx.x;
    int r  = gid >> 4;
    int sl = gid & 15;
    if (r >= n) return;
    int s0 = offs[r], d = cnt[r];
    const bool act = sl < 10;
    const float* gc = g + sl * 4;
    float4 acc = make_float4(0.f, 0.f, 0.f, 0.f);
    if (act) acc = *(const float4*)&gc[(size_t)r * OUTD];  // self loop
    for (int j0 = 0; j0 < d; j0 += 16) {
        int s = 0;
        if (j0 + sl < d) s = csr[s0 + j0 + sl];
        int m = min(16, d - j0);
        for (int jj = 0; jj < m; jj++) {
            int sj = __shfl(s, jj, 16);
            if (act) {
                float4 v = *(const float4*)&gc[(size_t)sj * OUTD];
                acc.x += v.x; acc.y += v.y; acc.z += v.z; acc.w += v.w;
            }
        }
    }
    if (act) {
        float dv = dinv[r];
        float4 bv = *(const float4*)&b2[sl * 4];
        float4 o;
        o.x = acc.x * dv + bv.x;
        o.y = acc.y * dv + bv.y;
        o.z = acc.z * dv + bv.z;
        o.w = acc.w * dv + bv.w;
        *(float4*)&out[(size_t)r * OUTD + sl * 4] = o;
    }
}

// ---------------- gemm2: g2 = dinv * (relu(dinv*acc1 + b1) @ W2) ----------------
__global__ void k_gemm2(const float* __restrict__ acc1, const float* __restrict__ b1,
                        const float* __restrict__ W2, const float* __restrict__ dinv,
                        float* __restrict__ g2, int n)
{
    int r = blockIdx.x * blockDim.x + threadIdx.x;
    if (r >= n) return;
    float dv = dinv[r];
    float h[HID];
#pragma unroll
    for (int k4 = 0; k4 < HID / 4; k4++) {
        float4 v  = *(const float4*)&acc1[(size_t)r * HID + k4 * 4];
        float4 bv = *(const float4*)&b1[k4 * 4];
        h[k4 * 4 + 0] = fmaxf(v.x * dv + bv.x, 0.f);
        h[k4 * 4 + 1] = fmaxf(v.y * dv + bv.y, 0.f);
        h[k4 * 4 + 2] = fmaxf(v.z * dv + bv.z, 0.f);
        h[k4 * 4 + 3] = fmaxf(v.w * dv + bv.w, 0.f);
    }
    float o[OUTD];
#pragma unroll
    for (int c = 0; c < OUTD; c++) o[c] = 0.f;
#pragma unroll
    for (int k = 0; k < HID; k++) {
        float hv = h[k];
        const float* wr = &W2[k * OUTD];  // uniform -> s_load
#pragma unroll
        for (int c = 0; c < OUTD; c++) o[c] += hv * wr[c];
    }
    float* gp = &g2[(size_t)r * OUTD];
#pragma unroll
    for (int c4 = 0; c4 < OUTD / 4; c4++) {
        float4 v;
        v.x = o[c4 * 4 + 0] * dv;
        v.y = o[c4 * 4 + 1] * dv;
        v.z = o[c4 * 4 + 2] * dv;
        v.w = o[c4 * 4 + 3] * dv;
        *(float4*)&gp[c4 * 4] = v;
    }
}

extern "C" void kernel_launch(void* const* d_in, const int* in_sizes, int n_in,
                              void* d_out, int out_size, void* d_ws, size_t ws_size,
                              hipStream_t stream)
{
    const float* x  = (const float*)d_in[0];
    const int*   ei = (const int*)d_in[1];
    const float* W1 = (const float*)d_in[2];
    const float* b1 = (const float*)d_in[3];
    const float* W2 = (const float*)d_in[4];
    const float* b2 = (const float*)d_in[5];
    float* out = (float*)d_out;

    const int n = in_sizes[0] / N_IN;  // 100000
    const int e = in_sizes[1] / 2;     // 1600000
    const int* src = ei;
    const int* dst = ei + e;

    char* w = (char*)d_ws;
    float* dinv   = (float*)w;            w += sizeof(float) * (size_t)((n + 3) & ~3);
    float* g1     = (float*)w;            w += sizeof(float) * (size_t)n * HID;
    float* acc1   = (float*)w;            w += sizeof(float) * (size_t)n * HID;
    float* g2     = (float*)w;            w += sizeof(float) * (size_t)n * OUTD;
    int*   cnt    = (int*)w;              w += sizeof(int) * (size_t)((n + 3) & ~3);
    int*   offs   = (int*)w;              w += sizeof(int) * (size_t)((n + 3) & ~3);
    int*   cursor = (int*)w;              w += sizeof(int) * (size_t)((n + 3) & ~3);
    int*   bsums  = (int*)w;              w += sizeof(int) * 1024;
    int*   csr    = (int*)w;              w += sizeof(int) * (size_t)e;

    const int nb = (n + 1023) / 1024;

    k_zero_i<<<(n + 255) / 256, 256, 0, stream>>>(cnt, n);
    k_count<<<(e + 255) / 256, 256, 0, stream>>>(dst, cnt, e);
    k_scan1<<<nb, 256, 0, stream>>>(cnt, offs, bsums, n);
    k_scan2<<<1, 256, 0, stream>>>(bsums, nb);
    k_scan3<<<(n + 255) / 256, 256, 0, stream>>>(offs, cursor, bsums, cnt, dinv, n);

    for (int wdx = 0; wdx < NWIN; wdx++) {
        int wlo = (int)((long)n * wdx / NWIN);
        int whi = (int)((long)n * (wdx + 1) / NWIN);
        k_fill_win<<<(e + 255) / 256, 256, 0, stream>>>(src, dst, cursor, csr, e, wlo, whi);
    }

    k_gemm1<<<(n + G1_ROWS - 1) / G1_ROWS, G1_T, 0, stream>>>(x, W1, dinv, g1, n);

    int t32 = n * 16;
    k_agg32<<<(t32 + 255) / 256, 256, 0, stream>>>(csr, offs, cnt, g1, acc1, n);

    k_gemm2<<<(n + 255) / 256, 256, 0, stream>>>(acc1, b1, W2, dinv, g2, n);

    int t40 = n * 16;
    k_agg40<<<(t40 + 255) / 256, 256, 0, stream>>>(csr, offs, cnt, g2, dinv, b2, out, n);
}

// Round 5
// 611.391 us; speedup vs baseline: 1.5581x; 1.0328x over previous
//
#include <hip/hip_runtime.h>
#include <hip/hip_bf16.h>

#define N_IN 512
#define HID 32
#define OUTD 40
#define NWIN 8  // fill windows: csr region per window ~800 KB -> L2-resident writes

typedef __attribute__((ext_vector_type(8))) short bf16x8;
typedef __attribute__((ext_vector_type(4))) float f32x4;

// ---------------- degree / CSR build ----------------

__global__ void k_zero_i(int* p, int n) {
    int i = blockIdx.x * blockDim.x + threadIdx.x;
    if (i < n) p[i] = 0;
}

__global__ void k_count(const int* __restrict__ dst, int* cnt, int e) {
    int i = blockIdx.x * blockDim.x + threadIdx.x;
    if (i < e) atomicAdd(&cnt[dst[i]], 1);
}

// block-local exclusive scan: 256 threads x 4 elems = 1024/block
__global__ __launch_bounds__(256) void k_scan1(const int* __restrict__ cnt,
                                               int* __restrict__ offs,
                                               int* __restrict__ bsums, int n)
{
    __shared__ int sm[256];
    int t = threadIdx.x;
    int base = blockIdx.x * 1024 + t * 4;
    int a0 = (base + 0 < n) ? cnt[base + 0] : 0;
    int a1 = (base + 1 < n) ? cnt[base + 1] : 0;
    int a2 = (base + 2 < n) ? cnt[base + 2] : 0;
    int a3 = (base + 3 < n) ? cnt[base + 3] : 0;
    int s = a0 + a1 + a2 + a3;
    sm[t] = s;
    __syncthreads();
#pragma unroll
    for (int off = 1; off < 256; off <<= 1) {
        int v = (t >= off) ? sm[t - off] : 0;
        __syncthreads();
        sm[t] += v;
        __syncthreads();
    }
    int excl = sm[t] - s;
    if (base + 0 < n) offs[base + 0] = excl;
    if (base + 1 < n) offs[base + 1] = excl + a0;
    if (base + 2 < n) offs[base + 2] = excl + a0 + a1;
    if (base + 3 < n) offs[base + 3] = excl + a0 + a1 + a2;
    if (t == 255) bsums[blockIdx.x] = sm[255];
}

// single-block exclusive scan of block sums (nb <= 256)
__global__ __launch_bounds__(256) void k_scan2(int* bsums, int nb)
{
    __shared__ int sm[256];
    int t = threadIdx.x;
    int s = (t < nb) ? bsums[t] : 0;
    sm[t] = s;
    __syncthreads();
#pragma unroll
    for (int off = 1; off < 256; off <<= 1) {
        int v = (t >= off) ? sm[t - off] : 0;
        __syncthreads();
        sm[t] += v;
        __syncthreads();
    }
    if (t < nb) bsums[t] = sm[t] - s;
}

// finalize offsets, init cursor, compute dinv = rsqrt(1 + indeg)
__global__ void k_scan3(int* __restrict__ offs, int* __restrict__ cursor,
                        const int* __restrict__ bsums, const int* __restrict__ cnt,
                        float* __restrict__ dinv, int n)
{
    int i = blockIdx.x * blockDim.x + threadIdx.x;
    if (i >= n) return;
    int o = offs[i] + bsums[i >> 10];
    offs[i] = o;
    cursor[i] = o;
    dinv[i] = rsqrtf((float)(cnt[i] + 1));
}

// windowed fill: csr writes land in ~800 KB contiguous region (L2-resident)
__global__ void k_fill_win(const int* __restrict__ src, const int* __restrict__ dst,
                           int* cursor, int* __restrict__ csr, int e, int wlo, int whi)
{
    int i = blockIdx.x * blockDim.x + threadIdx.x;
    if (i >= e) return;
    int d = dst[i];
    if (d < wlo || d >= whi) return;
    int p = atomicAdd(&cursor[d], 1);
    csr[p] = src[i];
}

// ---------------- W1 -> MFMA B-fragment layout, split bf16 hi/lo ----------------
// frag index: idx = ((kstep*2 + ntile)*64 + lane)*8 + j
//   k = kstep*32 + (lane>>4)*8 + j ; ncol = ntile*16 + (lane&15)
__global__ void k_convw(const float* __restrict__ W, unsigned short* __restrict__ wfh,
                        unsigned short* __restrict__ wfl)
{
    int idx = blockIdx.x * blockDim.x + threadIdx.x;  // 16*2*64*8 = 16384
    int j     = idx & 7;
    int lane  = (idx >> 3) & 63;
    int ntile = (idx >> 9) & 1;
    int kstep = idx >> 10;
    int k    = kstep * 32 + (lane >> 4) * 8 + j;
    int ncol = ntile * 16 + (lane & 15);
    float v = W[k * HID + ncol];
    unsigned u = __builtin_bit_cast(unsigned, v);
    unsigned short h = (unsigned short)(u >> 16);  // truncate -> hi
    float hv = __builtin_bit_cast(float, u & 0xFFFF0000u);
    float rem = v - hv;
    unsigned ur = __builtin_bit_cast(unsigned, rem);
    ur += 0x7FFF + ((ur >> 16) & 1);               // RNE -> lo
    wfh[idx] = h;
    wfl[idx] = (unsigned short)(ur >> 16);
}

// ---------------- gemm1 (MFMA split-bf16): g1 = dinv * (x @ W1) ----------------
// 4 waves/block, wave = 16 rows x 32 cols. No LDS, no barriers, no s_loads in loop.
__global__ __launch_bounds__(256) void k_gemm1(
    const float* __restrict__ x,
    const unsigned short* __restrict__ wfh, const unsigned short* __restrict__ wfl,
    const float* __restrict__ dinv, float* __restrict__ g1, int n)
{
    const int t    = threadIdx.x;
    const int lane = t & 63;
    const int wave = t >> 6;
    const int m    = lane & 15;
    const int quad = lane >> 4;
    const int row0 = blockIdx.x * 64 + wave * 16;

    int arow = row0 + m;
    if (arow >= n) arow = n - 1;  // clamp: A row m only feeds output row m (unstored)
    const float* xp = x + (size_t)arow * N_IN + quad * 8;

    f32x4 acc0 = {0.f, 0.f, 0.f, 0.f};
    f32x4 acc1 = {0.f, 0.f, 0.f, 0.f};

    for (int ks = 0; ks < 16; ks++) {
        float4 xa = *(const float4*)(xp + ks * 32);
        float4 xb = *(const float4*)(xp + ks * 32 + 4);
        float xe[8] = {xa.x, xa.y, xa.z, xa.w, xb.x, xb.y, xb.z, xb.w};
        bf16x8 ah, al;
#pragma unroll
        for (int j = 0; j < 8; j++) {
            unsigned u = __builtin_bit_cast(unsigned, xe[j]);
            ah[j] = (short)(u >> 16);                           // truncate -> hi
            float hv = __builtin_bit_cast(float, u & 0xFFFF0000u);
            float rem = xe[j] - hv;
            unsigned ur = __builtin_bit_cast(unsigned, rem);
            ur += 0x7FFF + ((ur >> 16) & 1);                    // RNE -> lo
            al[j] = (short)(ur >> 16);
        }
        bf16x8 bh0 = *(const bf16x8*)(wfh + ((size_t)(ks * 2 + 0) * 64 + lane) * 8);
        bf16x8 bh1 = *(const bf16x8*)(wfh + ((size_t)(ks * 2 + 1) * 64 + lane) * 8);
        bf16x8 bl0 = *(const bf16x8*)(wfl + ((size_t)(ks * 2 + 0) * 64 + lane) * 8);
        bf16x8 bl1 = *(const bf16x8*)(wfl + ((size_t)(ks * 2 + 1) * 64 + lane) * 8);

        acc0 = __builtin_amdgcn_mfma_f32_16x16x32_bf16(ah, bh0, acc0, 0, 0, 0);
        acc0 = __builtin_amdgcn_mfma_f32_16x16x32_bf16(al, bh0, acc0, 0, 0, 0);
        acc0 = __builtin_amdgcn_mfma_f32_16x16x32_bf16(ah, bl0, acc0, 0, 0, 0);
        acc1 = __builtin_amdgcn_mfma_f32_16x16x32_bf16(ah, bh1, acc1, 0, 0, 0);
        acc1 = __builtin_amdgcn_mfma_f32_16x16x32_bf16(al, bh1, acc1, 0, 0, 0);
        acc1 = __builtin_amdgcn_mfma_f32_16x16x32_bf16(ah, bl1, acc1, 0, 0, 0);
    }

    // C/D: col = lane&15 (+16 for ntile1), row = quad*4 + r  [m89-verified mapping]
#pragma unroll
    for (int r = 0; r < 4; r++) {
        int row = row0 + quad * 4 + r;
        if (row < n) {
            float dv = dinv[row];
            g1[(size_t)row * HID + m]      = acc0[r] * dv;
            g1[(size_t)row * HID + 16 + m] = acc1[r] * dv;
        }
    }
}

// ---------------- cooperative gather-aggregate: 16 lanes per node ----------------

__global__ void k_agg32(const int* __restrict__ csr, const int* __restrict__ offs,
                        const int* __restrict__ cnt, const float* __restrict__ g,
                        float* __restrict__ acc1, int n)
{
    int gid = blockIdx.x * blockDim.x + threadIdx.x;
    int r  = gid >> 4;
    int sl = gid & 15;
    if (r >= n) return;
    int s0 = offs[r], d = cnt[r];
    const bool act = sl < 8;
    const float* gc = g + sl * 4;
    float4 acc = make_float4(0.f, 0.f, 0.f, 0.f);
    if (act) acc = *(const float4*)&gc[(size_t)r * HID];  // self loop
    for (int j0 = 0; j0 < d; j0 += 16) {
        int s = 0;
        if (j0 + sl < d) s = csr[s0 + j0 + sl];
        int mlim = min(16, d - j0);
        for (int jj = 0; jj < mlim; jj++) {
            int sj = __shfl(s, jj, 16);
            if (act) {
                float4 v = *(const float4*)&gc[(size_t)sj * HID];
                acc.x += v.x; acc.y += v.y; acc.z += v.z; acc.w += v.w;
            }
        }
    }
    if (act) *(float4*)&acc1[(size_t)r * HID + sl * 4] = acc;
}

__global__ void k_agg40(const int* __restrict__ csr, const int* __restrict__ offs,
                        const int* __restrict__ cnt, const float* __restrict__ g,
                        const float* __restrict__ dinv, const float* __restrict__ b2,
                        float* __restrict__ out, int n)
{
    int gid = blockIdx.x * blockDim.x + threadIdx.x;
    int r  = gid >> 4;
    int sl = gid & 15;
    if (r >= n) return;
    int s0 = offs[r], d = cnt[r];
    const bool act = sl < 10;
    const float* gc = g + sl * 4;
    float4 acc = make_float4(0.f, 0.f, 0.f, 0.f);
    if (act) acc = *(const float4*)&gc[(size_t)r * OUTD];  // self loop
    for (int j0 = 0; j0 < d; j0 += 16) {
        int s = 0;
        if (j0 + sl < d) s = csr[s0 + j0 + sl];
        int mlim = min(16, d - j0);
        for (int jj = 0; jj < mlim; jj++) {
            int sj = __shfl(s, jj, 16);
            if (act) {
                float4 v = *(const float4*)&gc[(size_t)sj * OUTD];
                acc.x += v.x; acc.y += v.y; acc.z += v.z; acc.w += v.w;
            }
        }
    }
    if (act) {
        float dv = dinv[r];
        float4 bv = *(const float4*)&b2[sl * 4];
        float4 o;
        o.x = acc.x * dv + bv.x;
        o.y = acc.y * dv + bv.y;
        o.z = acc.z * dv + bv.z;
        o.w = acc.w * dv + bv.w;
        *(float4*)&out[(size_t)r * OUTD + sl * 4] = o;
    }
}

// ---------------- gemm2: g2 = dinv * (relu(dinv*acc1 + b1) @ W2) ----------------
__global__ void k_gemm2(const float* __restrict__ acc1, const float* __restrict__ b1,
                        const float* __restrict__ W2, const float* __restrict__ dinv,
                        float* __restrict__ g2, int n)
{
    int r = blockIdx.x * blockDim.x + threadIdx.x;
    if (r >= n) return;
    float dv = dinv[r];
    float h[HID];
#pragma unroll
    for (int k4 = 0; k4 < HID / 4; k4++) {
        float4 v  = *(const float4*)&acc1[(size_t)r * HID + k4 * 4];
        float4 bv = *(const float4*)&b1[k4 * 4];
        h[k4 * 4 + 0] = fmaxf(v.x * dv + bv.x, 0.f);
        h[k4 * 4 + 1] = fmaxf(v.y * dv + bv.y, 0.f);
        h[k4 * 4 + 2] = fmaxf(v.z * dv + bv.z, 0.f);
        h[k4 * 4 + 3] = fmaxf(v.w * dv + bv.w, 0.f);
    }
    float o[OUTD];
#pragma unroll
    for (int c = 0; c < OUTD; c++) o[c] = 0.f;
#pragma unroll
    for (int k = 0; k < HID; k++) {
        float hv = h[k];
        const float* wr = &W2[k * OUTD];  // uniform -> s_load
#pragma unroll
        for (int c = 0; c < OUTD; c++) o[c] += hv * wr[c];
    }
    float* gp = &g2[(size_t)r * OUTD];
#pragma unroll
    for (int c4 = 0; c4 < OUTD / 4; c4++) {
        float4 v;
        v.x = o[c4 * 4 + 0] * dv;
        v.y = o[c4 * 4 + 1] * dv;
        v.z = o[c4 * 4 + 2] * dv;
        v.w = o[c4 * 4 + 3] * dv;
        *(float4*)&gp[c4 * 4] = v;
    }
}

extern "C" void kernel_launch(void* const* d_in, const int* in_sizes, int n_in,
                              void* d_out, int out_size, void* d_ws, size_t ws_size,
                              hipStream_t stream)
{
    const float* x  = (const float*)d_in[0];
    const int*   ei = (const int*)d_in[1];
    const float* W1 = (const float*)d_in[2];
    const float* b1 = (const float*)d_in[3];
    const float* W2 = (const float*)d_in[4];
    const float* b2 = (const float*)d_in[5];
    float* out = (float*)d_out;

    const int n = in_sizes[0] / N_IN;  // 100000
    const int e = in_sizes[1] / 2;     // 1600000
    const int* src = ei;
    const int* dst = ei + e;

    char* w = (char*)d_ws;
    float* dinv   = (float*)w;            w += sizeof(float) * (size_t)((n + 3) & ~3);
    float* g1     = (float*)w;            w += sizeof(float) * (size_t)n * HID;
    float* acc1   = (float*)w;            w += sizeof(float) * (size_t)n * HID;
    float* g2     = (float*)w;            w += sizeof(float) * (size_t)n * OUTD;
    int*   cnt    = (int*)w;              w += sizeof(int) * (size_t)((n + 3) & ~3);
    int*   offs   = (int*)w;              w += sizeof(int) * (size_t)((n + 3) & ~3);
    int*   cursor = (int*)w;              w += sizeof(int) * (size_t)((n + 3) & ~3);
    int*   bsums  = (int*)w;              w += sizeof(int) * 1024;
    unsigned short* wfh = (unsigned short*)w;  w += sizeof(unsigned short) * 16384;
    unsigned short* wfl = (unsigned short*)w;  w += sizeof(unsigned short) * 16384;
    int*   csr    = (int*)w;              w += sizeof(int) * (size_t)e;

    const int nb = (n + 1023) / 1024;

    k_zero_i<<<(n + 255) / 256, 256, 0, stream>>>(cnt, n);
    k_count<<<(e + 255) / 256, 256, 0, stream>>>(dst, cnt, e);
    k_scan1<<<nb, 256, 0, stream>>>(cnt, offs, bsums, n);
    k_scan2<<<1, 256, 0, stream>>>(bsums, nb);
    k_scan3<<<(n + 255) / 256, 256, 0, stream>>>(offs, cursor, bsums, cnt, dinv, n);

    for (int wdx = 0; wdx < NWIN; wdx++) {
        int wlo = (int)((long)n * wdx / NWIN);
        int whi = (int)((long)n * (wdx + 1) / NWIN);
        k_fill_win<<<(e + 255) / 256, 256, 0, stream>>>(src, dst, cursor, csr, e, wlo, whi);
    }

    k_convw<<<64, 256, 0, stream>>>(W1, wfh, wfl);

    k_gemm1<<<(n + 63) / 64, 256, 0, stream>>>(x, wfh, wfl, dinv, g1, n);

    int t32 = n * 16;
    k_agg32<<<(t32 + 255) / 256, 256, 0, stream>>>(csr, offs, cnt, g1, acc1, n);

    k_gemm2<<<(n + 255) / 256, 256, 0, stream>>>(acc1, b1, W2, dinv, g2, n);

    int t40 = n * 16;
    k_agg40<<<(t40 + 255) / 256, 256, 0, stream>>>(csr, offs, cnt, g2, dinv, b2, out, n);
}